// Round 8
// baseline (114.402 us; speedup 1.0000x reference)
//
#include <hip/hip_runtime.h>

// CausalSelfAttention: B=2 S=2048 H=16 D=64 HID=1024, fp32 in/out, bf16 MFMA compute.
//
// R7 changes vs R6 (attn inner loop only — chain surgery):
//  - Deferred l-sum: per-lane partial l (rescale multiplies it; fs is q-uniform),
//    single cross-lane reduce AFTER the key loop. Removes 2 shfl/iter.
//  - Trigger-only max: per-lane max tree + __any(local > m+11) vcc check; full
//    cross-lane max only on the (rare) trigger. Removes 2 shfl/iter from the chain.
//  - Masked last iteration peeled out of the loop (no mask branch in main body).
//  Grid/balance/staging identical to R6 (1024 blocks, 4/CU, XCD-pinned, dbuf LDS).
//
// MFMA layout discipline: each MFMA's operand k-slot bijection is CHOSEN and used
// consistently for BOTH its A and B operands -> result invariant to the true HW
// bijection. QK uses sigma1(g,j)=g*8+j; PV uses sigma2(g,j)=(j>>2)*16+g*4+(j&3)
// (matches QK^T C/D register layout). C/D: col = lane&15, row = (lane>>4)*4 + reg.

typedef unsigned short u16;
typedef float f32x4 __attribute__((ext_vector_type(4)));
typedef __bf16 bf16x8 __attribute__((ext_vector_type(8)));
typedef unsigned short u16x4 __attribute__((ext_vector_type(4)));
typedef unsigned short u16x8 __attribute__((ext_vector_type(8)));

constexpr int Bn = 2, SEQ = 2048, NH = 16, HD = 64, HID = 1024;
constexpr size_t NX = (size_t)Bn * SEQ * HID;  // 4,194,304
constexpr size_t NW = (size_t)HID * HID;       // 1,048,576 = 1<<20

__device__ __forceinline__ u16 f2bf(float f) {
  unsigned u = __float_as_uint(f);
  u += 0x7fff + ((u >> 16) & 1);  // RNE
  return (u16)(u >> 16);
}

__device__ __forceinline__ f32x4 mfma16(bf16x8 a, bf16x8 b, f32x4 c) {
  return __builtin_amdgcn_mfma_f32_16x16x32_bf16(a, b, c, 0, 0, 0);
}

__device__ __forceinline__ void gload16(const u16* g, u16* l) {
  __builtin_amdgcn_global_load_lds(
      (const __attribute__((address_space(1))) unsigned int*)(const void*)g,
      (__attribute__((address_space(3))) unsigned int*)(void*)l, 16, 0, 0);
}

// One dispatch converting x, Wq, Wk, Wv, Wp to bf16.
__global__ void cvt_all(const float* __restrict__ x,
                        const float* __restrict__ Wq, const float* __restrict__ Wk,
                        const float* __restrict__ Wv, const float* __restrict__ Wp,
                        u16* __restrict__ xb, u16* __restrict__ wqb, u16* __restrict__ wkb,
                        u16* __restrict__ wvb, u16* __restrict__ wpb) {
  size_t i = ((size_t)blockIdx.x * blockDim.x + threadIdx.x) * 4;
  const float* s; u16* d; size_t off;
  if (i < NX) { s = x; d = xb; off = i; }
  else {
    size_t k = i - NX;
    int id = (int)(k >> 20);
    off = k & (NW - 1);
    s = (id == 0) ? Wq : (id == 1) ? Wk : (id == 2) ? Wv : Wp;
    d = (id == 0) ? wqb : (id == 1) ? wkb : (id == 2) ? wvb : wpb;
  }
  float4 v = *reinterpret_cast<const float4*>(s + off);
  u16x4 o = {f2bf(v.x), f2bf(v.y), f2bf(v.z), f2bf(v.w)};
  *reinterpret_cast<u16x4*>(d + off) = o;
}

// Fused QKV projection: grid (24 n-panels, 32 m-tiles); x-fastest dispatch ->
// weight panel x pinned to XCD x&7 (3 panels/XCD L2-resident).
// Q,K -> [b,h,s,d]; V -> [b,h,d,s] via LDS transpose epilogue.
__global__ __launch_bounds__(256) void qkv_gemm(
    const u16* __restrict__ A,
    const u16* __restrict__ W0, const u16* __restrict__ W1, const u16* __restrict__ W2,
    const float* __restrict__ b0, const float* __restrict__ b1, const float* __restrict__ b2,
    u16* __restrict__ out0, u16* __restrict__ out1, u16* __restrict__ out2)
{
  constexpr int K = HID;
  __shared__ u16 smem[16384];  // As[2]=smem[0..8191], Bs[2]=smem[8192..16383]; epilogue reuse 32KB
  const int tid = threadIdx.x;
  const int lane = tid & 63, w = tid >> 6;
  const int wr = w >> 1, wc = w & 1;
  const int l15 = lane & 15, g = lane >> 4;
  const int m0 = blockIdx.y * 128;
  const int n0g = blockIdx.x * 128;
  const int id = n0g >> 10;
  const int n0 = n0g & (HID - 1);
  const u16* Bm = (id == 0) ? W0 : (id == 1) ? W1 : W2;
  const float* bias = (id == 0) ? b0 : (id == 1) ? b1 : b2;

  auto stage = [&](int buf, int kt) {
#pragma unroll
    for (int i = 0; i < 2; i++) {
      int chunk = tid + 256 * i;
      int r = chunk >> 2, c = (chunk & 3) << 3;
      gload16(&A[(size_t)(m0 + r) * K + kt + c], &smem[buf * 4096 + chunk * 8]);
      gload16(&Bm[(size_t)(n0 + r) * K + kt + c], &smem[8192 + buf * 4096 + chunk * 8]);
    }
  };

  f32x4 acc[4][4] = {};
  stage(0, 0);

  for (int ki = 0; ki < 32; ki++) {
    const int buf = ki & 1;
    __syncthreads();  // vmcnt(0): stage(ki) landed (issued a full compute phase ago)
    if (ki + 1 < 32) stage(buf ^ 1, (ki + 1) * 32);
    const u16* As = &smem[buf * 4096];
    const u16* Bs = &smem[8192 + buf * 4096];
    bf16x8 af[4], bfr[4];
#pragma unroll
    for (int mi = 0; mi < 4; mi++)
      af[mi] = *reinterpret_cast<const bf16x8*>(&As[(wr * 64 + mi * 16 + l15) * 32 + g * 8]);
#pragma unroll
    for (int ni = 0; ni < 4; ni++)
      bfr[ni] = *reinterpret_cast<const bf16x8*>(&Bs[(wc * 64 + ni * 16 + l15) * 32 + g * 8]);
#pragma unroll
    for (int mi = 0; mi < 4; mi++)
#pragma unroll
      for (int ni = 0; ni < 4; ni++)
        acc[mi][ni] = mfma16(af[mi], bfr[ni], acc[mi][ni]);
  }

  float bv[4];
#pragma unroll
  for (int ni = 0; ni < 4; ni++) bv[ni] = bias[n0 + wc * 64 + ni * 16 + l15];

  if (id == 2) {
    // V^T: transpose 128(sq) x 128(d) tile through swizzled LDS, store along s.
    __syncthreads();  // K-loop LDS reads done everywhere; reuse smem
#pragma unroll
    for (int mi = 0; mi < 4; mi++)
#pragma unroll
      for (int ni = 0; ni < 4; ni++) {
        u16x4 pk;
#pragma unroll
        for (int r = 0; r < 4; r++) pk[r] = f2bf(acc[mi][ni][r] + bv[ni]);
        int d_loc = wc * 64 + ni * 16 + l15;
        int sq_base = wr * 64 + mi * 16 + g * 4;
        *reinterpret_cast<u16x4*>(
            &smem[d_loc * 128 + (sq_base ^ ((d_loc & 7) << 4))]) = pk;
      }
    __syncthreads();
    const int bb = m0 >> 11;
    const int sq0 = m0 & (SEQ - 1);
#pragma unroll
    for (int i = 0; i < 8; i++) {
      int chunk = tid + 256 * i;           // 0..2047
      int d_loc = chunk >> 4;              // 0..127
      int sqc = (chunk & 15) << 3;         // 0..120, step 8
      u16x8 val = *reinterpret_cast<const u16x8*>(
          &smem[d_loc * 128 + (sqc ^ ((d_loc & 7) << 4))]);
      int gn = n0 + d_loc;
      int hh = gn >> 6, dd = gn & 63;
      *reinterpret_cast<u16x8*>(
          &out2[((size_t)(bb * NH + hh) * HD + dd) * SEQ + sq0 + sqc]) = val;
    }
  } else {
    u16* out = (id == 0) ? out0 : out1;
#pragma unroll
    for (int mi = 0; mi < 4; mi++)
#pragma unroll
      for (int ni = 0; ni < 4; ni++)
#pragma unroll
        for (int r = 0; r < 4; r++) {
          int gm = m0 + wr * 64 + mi * 16 + g * 4 + r;
          int gn = n0 + wc * 64 + ni * 16 + l15;
          int bb = gm >> 11, sq = gm & (SEQ - 1);
          int hh = gn >> 6, d = gn & 63;
          out[((size_t)(bb * NH + hh) * SEQ + sq) * HD + d] = f2bf(acc[mi][ni][r] + bv[ni]);
        }
  }
}

// Output projection: out = Y @ Wp^T + bp, fp32. 64(M)x128(N) tiles, grid (8, 64):
// weight panel x pinned to XCD x (exactly one 256KB panel per XCD).
__global__ __launch_bounds__(256) void gemm_out(
    const u16* __restrict__ A, const u16* __restrict__ Bm,
    const float* __restrict__ bias, float* __restrict__ out)
{
  constexpr int K = HID, N = HID;
  __shared__ u16 As[2][64 * 32];
  __shared__ u16 Bs[2][128 * 32];
  const int tid = threadIdx.x;
  const int lane = tid & 63, w = tid >> 6;
  const int l15 = lane & 15, g = lane >> 4;
  const int m0 = blockIdx.y * 64, n0 = blockIdx.x * 128;

  auto stage = [&](int buf, int kt) {
    {
      int r = tid >> 2, c = (tid & 3) << 3;
      gload16(&A[(size_t)(m0 + r) * K + kt + c], &As[buf][tid * 8]);
    }
#pragma unroll
    for (int i = 0; i < 2; i++) {
      int chunk = tid + 256 * i;
      int r = chunk >> 2, c = (chunk & 3) << 3;
      gload16(&Bm[(size_t)(n0 + r) * K + kt + c], &Bs[buf][chunk * 8]);
    }
  };

  f32x4 acc[4][2] = {};
  stage(0, 0);

  for (int ki = 0; ki < 32; ki++) {
    const int buf = ki & 1;
    __syncthreads();
    if (ki + 1 < 32) stage(buf ^ 1, (ki + 1) * 32);
    bf16x8 af[4], bfr[2];
#pragma unroll
    for (int mi = 0; mi < 4; mi++)
      af[mi] = *reinterpret_cast<const bf16x8*>(&As[buf][(mi * 16 + l15) * 32 + g * 8]);
#pragma unroll
    for (int ni = 0; ni < 2; ni++)
      bfr[ni] = *reinterpret_cast<const bf16x8*>(&Bs[buf][(w * 32 + ni * 16 + l15) * 32 + g * 8]);
#pragma unroll
    for (int mi = 0; mi < 4; mi++)
#pragma unroll
      for (int ni = 0; ni < 2; ni++)
        acc[mi][ni] = mfma16(af[mi], bfr[ni], acc[mi][ni]);
  }

  float bv[2];
#pragma unroll
  for (int ni = 0; ni < 2; ni++) bv[ni] = bias[n0 + w * 32 + ni * 16 + l15];

#pragma unroll
  for (int mi = 0; mi < 4; mi++)
#pragma unroll
    for (int ni = 0; ni < 2; ni++)
#pragma unroll
      for (int r = 0; r < 4; r++) {
        int gm = m0 + mi * 16 + g * 4 + r;
        int gn = n0 + w * 32 + ni * 16 + l15;
        out[(size_t)gm * N + gn] = acc[mi][ni][r] + bv[ni];
      }
}

// Flash attention, causal. Grid 1024 (all co-resident, 4 blocks/CU).
// bid -> (xcd, bh, tile) with per-CU balanced tiles {24+s, 23-s, 8+s, 7-s}.
// Double-buffered K/V LDS (32KB), stage-after-barrier. Swapped QK^T; P in regs.
// Chain-minimized softmax: per-lane l partial, trigger-only max (no per-iter shfl).
__global__ __launch_bounds__(256, 4) void attn_kernel(
    const u16* __restrict__ Q, const u16* __restrict__ Kt,
    const u16* __restrict__ Vt, u16* __restrict__ Y)
{
  __shared__ u16 smK[2][4096];  // [buf][64 keys][64 d]   (swizzled slots)
  __shared__ u16 smV[2][4096];  // [buf][64 d][64 keys]   (swizzled slots)
  const int tid = threadIdx.x;
  const int lane = tid & 63, w = tid >> 6;
  const int l15 = lane & 15, g = lane >> 4;
  const int bid = blockIdx.x;          // 0..1023
  const int q = bid >> 8;              // round 0..3 (same CU across rounds)
  const int rr = bid & 255;
  const int xcd = rr & 7;
  const int cu = (rr >> 3) & 31;       // CU slot within XCD
  const int bh = xcd * 4 + (cu & 3);   // 4 bh pinned per XCD
  const int s = cu >> 2;               // 0..7
  int tile;
  if (q == 0) tile = 24 + s;
  else if (q == 1) tile = 23 - s;
  else if (q == 2) tile = 8 + s;
  else tile = 7 - s;
  const int b = bh >> 4, h = bh & 15;
  const int xs = l15 & 7;  // read-side XOR

  const int nt = tile + 1;
  const int q0 = tile * 64 + w * 16;
  const int qg = q0 + l15;

  const size_t bhs = (size_t)bh;
  const u16* Qp = Q + bhs * SEQ * HD;
  const u16* Kp = Kt + bhs * SEQ * HD;
  const u16* Vp = Vt + bhs * HD * SEQ;  // [d][s]

  int srow[2], sslot[2];
#pragma unroll
  for (int it = 0; it < 2; it++) {
    int idx = it * 256 + tid;
    srow[it] = idx >> 3;
    sslot[it] = (idx & 7) ^ (srow[it] & 7);  // pre-swizzled global source slot
  }
  auto stage = [&](int buf, int kt) {
#pragma unroll
    for (int it = 0; it < 2; it++) {
      int idx = it * 256 + tid;
      gload16(Kp + (size_t)(kt + srow[it]) * HD + sslot[it] * 8, &smK[buf][idx * 8]);
      gload16(Vp + (size_t)srow[it] * SEQ + kt + sslot[it] * 8, &smV[buf][idx * 8]);
    }
  };

  const float QSC = 0.125f * 1.44269504088896f;  // 1/sqrt(64) * log2(e)
  const float NEG = -__builtin_inff();

  // Q fragments (B operand, sigma1)
  bf16x8 tq0 = *reinterpret_cast<const bf16x8*>(Qp + (size_t)qg * HD + g * 8);
  bf16x8 tq1 = *reinterpret_cast<const bf16x8*>(Qp + (size_t)qg * HD + 32 + g * 8);
  stage(0, 0);
  bf16x8 qf[2];
#pragma unroll
  for (int jj = 0; jj < 8; jj++) {
    qf[0][jj] = (__bf16)((float)tq0[jj] * QSC);
    qf[1][jj] = (__bf16)((float)tq1[jj] * QSC);
  }

  float m_run = NEG;
  float l_lane = 0.0f;   // per-lane partial; cross-lane reduced AFTER the loop
  f32x4 o[4] = {};       // O^T[d][q]: d = db*16 + g*4 + r, q = l15

  // one iteration body; MASKED resolves to a constant after inlining
  auto iter_body = [&](int t, bool MASKED) __attribute__((always_inline)) {
    const int kt = t * 64;
    const int buf = t & 1;
    __syncthreads();  // stage(t) landed (issued a full iteration ago); buf^1 readers done
    if (t + 1 < nt) stage(buf ^ 1, kt + 64);
    const u16* K_ = smK[buf];
    const u16* V_ = smV[buf];

    // ---- QK^T: S^T (log2 domain), key = kt + sub*16 + g*4 + r, q = l15
    f32x4 sa[4];
#pragma unroll
    for (int sub = 0; sub < 4; sub++) {
      int row = sub * 16 + l15;
      bf16x8 k0 = *reinterpret_cast<const bf16x8*>(&K_[row * 64 + ((0 + g) ^ xs) * 8]);
      bf16x8 k1 = *reinterpret_cast<const bf16x8*>(&K_[row * 64 + ((4 + g) ^ xs) * 8]);
      f32x4 a = {0.f, 0.f, 0.f, 0.f};
      a = mfma16(k0, qf[0], a);
      a = mfma16(k1, qf[1], a);
      sa[sub] = a;
    }

    float p[16];
    if (MASKED) {
#pragma unroll
      for (int sub = 0; sub < 4; sub++)
#pragma unroll
        for (int r = 0; r < 4; r++) {
          int key = kt + sub * 16 + g * 4 + r;
          p[sub * 4 + r] = (key <= qg) ? sa[sub][r] : NEG;
        }
    } else {
#pragma unroll
      for (int sub = 0; sub < 4; sub++)
#pragma unroll
        for (int r = 0; r < 4; r++) p[sub * 4 + r] = sa[sub][r];
    }

    // ---- per-LANE max tree (no cross-lane shfl in the common path)
    float a0 = fmaxf(fmaxf(p[0], p[1]), p[2]);
    float a1 = fmaxf(fmaxf(p[3], p[4]), p[5]);
    float a2 = fmaxf(fmaxf(p[6], p[7]), p[8]);
    float a3 = fmaxf(fmaxf(p[9], p[10]), p[11]);
    float a4 = fmaxf(fmaxf(p[12], p[13]), p[14]);
    float b0 = fmaxf(fmaxf(a0, a1), p[15]);
    float tloc = fmaxf(fmaxf(b0, a2), fmaxf(a3, a4));

    // trigger-only rescale: rare (first tile, then ~never for N(0,1) scores)
    if (__any(tloc > m_run + 11.0f)) {
      float tmax = tloc;
      tmax = fmaxf(tmax, __shfl_xor(tmax, 16));
      tmax = fmaxf(tmax, __shfl_xor(tmax, 32));
      float mnew = fmaxf(m_run, tmax);
      float fs = __builtin_amdgcn_exp2f(m_run - mnew);  // 0 when m_run=-inf
      l_lane *= fs;
#pragma unroll
      for (int db = 0; db < 4; db++) o[db] *= fs;
      m_run = mnew;
    }

    // ---- P = 2^(p - m_run); per-lane partial sum; pack via compiler cvt_pk
    float pe[16];
    float s4[4] = {0.f, 0.f, 0.f, 0.f};
#pragma unroll
    for (int i = 0; i < 16; i++) {
      pe[i] = __builtin_amdgcn_exp2f(p[i] - m_run);
      s4[i & 3] += pe[i];
    }

    // ---- O^T += V^T * P^T; sigma2(g,j) = (j>>2)*16 + g*4 + (j&3)
#pragma unroll
    for (int half = 0; half < 2; half++) {
      bf16x8 pb;
#pragma unroll
      for (int jj = 0; jj < 8; jj++) pb[jj] = (__bf16)pe[8 * half + jj];
      const int s0 = ((4 * half + (g >> 1)) ^ xs) * 8 + 4 * (g & 1);
      const int s1 = ((4 * half + 2 + (g >> 1)) ^ xs) * 8 + 4 * (g & 1);
#pragma unroll
      for (int db = 0; db < 4; db++) {
        int vbase = (db * 16 + l15) * 64;
        u16x4 v0 = *reinterpret_cast<const u16x4*>(&V_[vbase + s0]);
        u16x4 v1 = *reinterpret_cast<const u16x4*>(&V_[vbase + s1]);
        u16x8 vau;
#pragma unroll
        for (int jj = 0; jj < 4; jj++) { vau[jj] = v0[jj]; vau[jj + 4] = v1[jj]; }
        bf16x8 va = __builtin_bit_cast(bf16x8, vau);
        o[db] = mfma16(va, pb, o[db]);
      }
    }

    l_lane += (s4[0] + s4[1]) + (s4[2] + s4[3]);
  };

  for (int t = 0; t < nt - 1; t++) iter_body(t, false);
  iter_body(nt - 1, true);  // peeled: causal mask only here

  // ---- final cross-lane l reduce (once per tile, not per iteration)
  float l_tot = l_lane;
  l_tot += __shfl_xor(l_tot, 16);
  l_tot += __shfl_xor(l_tot, 32);
  float rl = 1.0f / l_tot;
#pragma unroll
  for (int db = 0; db < 4; db++) {
    u16x4 yo;
#pragma unroll
    for (int r = 0; r < 4; r++) yo[r] = f2bf(o[db][r] * rl);
    *reinterpret_cast<u16x4*>(
        Y + ((size_t)(b * SEQ) + qg) * HID + h * HD + db * 16 + g * 4) = yo;
  }
}

extern "C" void kernel_launch(void* const* d_in, const int* in_sizes, int n_in,
                              void* d_out, int out_size, void* d_ws, size_t ws_size,
                              hipStream_t stream) {
  const float* x  = (const float*)d_in[0];
  const float* Wq = (const float*)d_in[1];
  const float* bq = (const float*)d_in[2];
  const float* Wk = (const float*)d_in[3];
  const float* bk = (const float*)d_in[4];
  const float* Wv = (const float*)d_in[5];
  const float* bv = (const float*)d_in[6];
  const float* Wp = (const float*)d_in[7];
  const float* bp = (const float*)d_in[8];

  u16* ws = (u16*)d_ws;
  u16* xb  = ws; ws += NX;
  u16* wqb = ws; ws += NW;
  u16* wkb = ws; ws += NW;
  u16* wvb = ws; ws += NW;
  u16* wpb = ws; ws += NW;
  u16* Qb  = ws; ws += NX;
  u16* Kb  = ws; ws += NX;
  u16* Vtb = ws; ws += NX;
  u16* Yb  = ws; ws += NX;   // total ~48 MB of d_ws

  const unsigned cvtBlocks = (unsigned)((NX + 4 * NW) / 4 / 256);  // 8192
  cvt_all<<<cvtBlocks, 256, 0, stream>>>(x, Wq, Wk, Wv, Wp, xb, wqb, wkb, wvb, wpb);

  qkv_gemm<<<dim3(24, 32), 256, 0, stream>>>(xb, wqb, wkb, wvb, bq, bk, bv, Qb, Kb, Vtb);

  attn_kernel<<<dim3(1024), 256, 0, stream>>>(Qb, Kb, Vtb, Yb);

  gemm_out<<<dim3(8, 64), 256, 0, stream>>>(Yb, wpb, bp, (float*)d_out);
}

// Round 9
// 114.338 us; speedup vs baseline: 1.0006x; 1.0006x over previous
//
#include <hip/hip_runtime.h>

// CausalSelfAttention: B=2 S=2048 H=16 D=64 HID=1024, fp32 in/out, bf16 MFMA compute.
//
// R7 changes vs R6 (attn inner loop only — chain surgery):
//  - Deferred l-sum: per-lane partial l (rescale multiplies it; fs is q-uniform),
//    single cross-lane reduce AFTER the key loop. Removes 2 shfl/iter.
//  - Trigger-only max: per-lane max tree + __any(local > m+11) vcc check; full
//    cross-lane max only on the (rare) trigger. Removes 2 shfl/iter from the chain.
//  - Masked last iteration peeled out of the loop (no mask branch in main body).
//  Grid/balance/staging identical to R6 (1024 blocks, 4/CU, XCD-pinned, dbuf LDS).
//
// MFMA layout discipline: each MFMA's operand k-slot bijection is CHOSEN and used
// consistently for BOTH its A and B operands -> result invariant to the true HW
// bijection. QK uses sigma1(g,j)=g*8+j; PV uses sigma2(g,j)=(j>>2)*16+g*4+(j&3)
// (matches QK^T C/D register layout). C/D: col = lane&15, row = (lane>>4)*4 + reg.

typedef unsigned short u16;
typedef float f32x4 __attribute__((ext_vector_type(4)));
typedef __bf16 bf16x8 __attribute__((ext_vector_type(8)));
typedef unsigned short u16x4 __attribute__((ext_vector_type(4)));
typedef unsigned short u16x8 __attribute__((ext_vector_type(8)));

constexpr int Bn = 2, SEQ = 2048, NH = 16, HD = 64, HID = 1024;
constexpr size_t NX = (size_t)Bn * SEQ * HID;  // 4,194,304
constexpr size_t NW = (size_t)HID * HID;       // 1,048,576 = 1<<20

__device__ __forceinline__ u16 f2bf(float f) {
  unsigned u = __float_as_uint(f);
  u += 0x7fff + ((u >> 16) & 1);  // RNE
  return (u16)(u >> 16);
}

__device__ __forceinline__ f32x4 mfma16(bf16x8 a, bf16x8 b, f32x4 c) {
  return __builtin_amdgcn_mfma_f32_16x16x32_bf16(a, b, c, 0, 0, 0);
}

__device__ __forceinline__ void gload16(const u16* g, u16* l) {
  __builtin_amdgcn_global_load_lds(
      (const __attribute__((address_space(1))) unsigned int*)(const void*)g,
      (__attribute__((address_space(3))) unsigned int*)(void*)l, 16, 0, 0);
}

// One dispatch converting x, Wq, Wk, Wv, Wp to bf16.
__global__ void cvt_all(const float* __restrict__ x,
                        const float* __restrict__ Wq, const float* __restrict__ Wk,
                        const float* __restrict__ Wv, const float* __restrict__ Wp,
                        u16* __restrict__ xb, u16* __restrict__ wqb, u16* __restrict__ wkb,
                        u16* __restrict__ wvb, u16* __restrict__ wpb) {
  size_t i = ((size_t)blockIdx.x * blockDim.x + threadIdx.x) * 4;
  const float* s; u16* d; size_t off;
  if (i < NX) { s = x; d = xb; off = i; }
  else {
    size_t k = i - NX;
    int id = (int)(k >> 20);
    off = k & (NW - 1);
    s = (id == 0) ? Wq : (id == 1) ? Wk : (id == 2) ? Wv : Wp;
    d = (id == 0) ? wqb : (id == 1) ? wkb : (id == 2) ? wvb : wpb;
  }
  float4 v = *reinterpret_cast<const float4*>(s + off);
  u16x4 o = {f2bf(v.x), f2bf(v.y), f2bf(v.z), f2bf(v.w)};
  *reinterpret_cast<u16x4*>(d + off) = o;
}

// Fused QKV projection: grid (24 n-panels, 32 m-tiles); x-fastest dispatch ->
// weight panel x pinned to XCD x&7 (3 panels/XCD L2-resident).
// Q,K -> [b,h,s,d]; V -> [b,h,d,s] via LDS transpose epilogue.
__global__ __launch_bounds__(256) void qkv_gemm(
    const u16* __restrict__ A,
    const u16* __restrict__ W0, const u16* __restrict__ W1, const u16* __restrict__ W2,
    const float* __restrict__ b0, const float* __restrict__ b1, const float* __restrict__ b2,
    u16* __restrict__ out0, u16* __restrict__ out1, u16* __restrict__ out2)
{
  constexpr int K = HID;
  __shared__ u16 smem[16384];  // As[2]=smem[0..8191], Bs[2]=smem[8192..16383]; epilogue reuse 32KB
  const int tid = threadIdx.x;
  const int lane = tid & 63, w = tid >> 6;
  const int wr = w >> 1, wc = w & 1;
  const int l15 = lane & 15, g = lane >> 4;
  const int m0 = blockIdx.y * 128;
  const int n0g = blockIdx.x * 128;
  const int id = n0g >> 10;
  const int n0 = n0g & (HID - 1);
  const u16* Bm = (id == 0) ? W0 : (id == 1) ? W1 : W2;
  const float* bias = (id == 0) ? b0 : (id == 1) ? b1 : b2;

  auto stage = [&](int buf, int kt) {
#pragma unroll
    for (int i = 0; i < 2; i++) {
      int chunk = tid + 256 * i;
      int r = chunk >> 2, c = (chunk & 3) << 3;
      gload16(&A[(size_t)(m0 + r) * K + kt + c], &smem[buf * 4096 + chunk * 8]);
      gload16(&Bm[(size_t)(n0 + r) * K + kt + c], &smem[8192 + buf * 4096 + chunk * 8]);
    }
  };

  f32x4 acc[4][4] = {};
  stage(0, 0);

  for (int ki = 0; ki < 32; ki++) {
    const int buf = ki & 1;
    __syncthreads();  // vmcnt(0): stage(ki) landed (issued a full compute phase ago)
    if (ki + 1 < 32) stage(buf ^ 1, (ki + 1) * 32);
    const u16* As = &smem[buf * 4096];
    const u16* Bs = &smem[8192 + buf * 4096];
    bf16x8 af[4], bfr[4];
#pragma unroll
    for (int mi = 0; mi < 4; mi++)
      af[mi] = *reinterpret_cast<const bf16x8*>(&As[(wr * 64 + mi * 16 + l15) * 32 + g * 8]);
#pragma unroll
    for (int ni = 0; ni < 4; ni++)
      bfr[ni] = *reinterpret_cast<const bf16x8*>(&Bs[(wc * 64 + ni * 16 + l15) * 32 + g * 8]);
#pragma unroll
    for (int mi = 0; mi < 4; mi++)
#pragma unroll
      for (int ni = 0; ni < 4; ni++)
        acc[mi][ni] = mfma16(af[mi], bfr[ni], acc[mi][ni]);
  }

  float bv[4];
#pragma unroll
  for (int ni = 0; ni < 4; ni++) bv[ni] = bias[n0 + wc * 64 + ni * 16 + l15];

  if (id == 2) {
    // V^T: transpose 128(sq) x 128(d) tile through swizzled LDS, store along s.
    __syncthreads();  // K-loop LDS reads done everywhere; reuse smem
#pragma unroll
    for (int mi = 0; mi < 4; mi++)
#pragma unroll
      for (int ni = 0; ni < 4; ni++) {
        u16x4 pk;
#pragma unroll
        for (int r = 0; r < 4; r++) pk[r] = f2bf(acc[mi][ni][r] + bv[ni]);
        int d_loc = wc * 64 + ni * 16 + l15;
        int sq_base = wr * 64 + mi * 16 + g * 4;
        *reinterpret_cast<u16x4*>(
            &smem[d_loc * 128 + (sq_base ^ ((d_loc & 7) << 4))]) = pk;
      }
    __syncthreads();
    const int bb = m0 >> 11;
    const int sq0 = m0 & (SEQ - 1);
#pragma unroll
    for (int i = 0; i < 8; i++) {
      int chunk = tid + 256 * i;           // 0..2047
      int d_loc = chunk >> 4;              // 0..127
      int sqc = (chunk & 15) << 3;         // 0..120, step 8
      u16x8 val = *reinterpret_cast<const u16x8*>(
          &smem[d_loc * 128 + (sqc ^ ((d_loc & 7) << 4))]);
      int gn = n0 + d_loc;
      int hh = gn >> 6, dd = gn & 63;
      *reinterpret_cast<u16x8*>(
          &out2[((size_t)(bb * NH + hh) * HD + dd) * SEQ + sq0 + sqc]) = val;
    }
  } else {
    u16* out = (id == 0) ? out0 : out1;
#pragma unroll
    for (int mi = 0; mi < 4; mi++)
#pragma unroll
      for (int ni = 0; ni < 4; ni++)
#pragma unroll
        for (int r = 0; r < 4; r++) {
          int gm = m0 + wr * 64 + mi * 16 + g * 4 + r;
          int gn = n0 + wc * 64 + ni * 16 + l15;
          int bb = gm >> 11, sq = gm & (SEQ - 1);
          int hh = gn >> 6, d = gn & 63;
          out[((size_t)(bb * NH + hh) * SEQ + sq) * HD + d] = f2bf(acc[mi][ni][r] + bv[ni]);
        }
  }
}

// Output projection: out = Y @ Wp^T + bp, fp32. 64(M)x128(N) tiles, grid (8, 64):
// weight panel x pinned to XCD x (exactly one 256KB panel per XCD).
__global__ __launch_bounds__(256) void gemm_out(
    const u16* __restrict__ A, const u16* __restrict__ Bm,
    const float* __restrict__ bias, float* __restrict__ out)
{
  constexpr int K = HID, N = HID;
  __shared__ u16 As[2][64 * 32];
  __shared__ u16 Bs[2][128 * 32];
  const int tid = threadIdx.x;
  const int lane = tid & 63, w = tid >> 6;
  const int l15 = lane & 15, g = lane >> 4;
  const int m0 = blockIdx.y * 64, n0 = blockIdx.x * 128;

  auto stage = [&](int buf, int kt) {
    {
      int r = tid >> 2, c = (tid & 3) << 3;
      gload16(&A[(size_t)(m0 + r) * K + kt + c], &As[buf][tid * 8]);
    }
#pragma unroll
    for (int i = 0; i < 2; i++) {
      int chunk = tid + 256 * i;
      int r = chunk >> 2, c = (chunk & 3) << 3;
      gload16(&Bm[(size_t)(n0 + r) * K + kt + c], &Bs[buf][chunk * 8]);
    }
  };

  f32x4 acc[4][2] = {};
  stage(0, 0);

  for (int ki = 0; ki < 32; ki++) {
    const int buf = ki & 1;
    __syncthreads();
    if (ki + 1 < 32) stage(buf ^ 1, (ki + 1) * 32);
    bf16x8 af[4], bfr[2];
#pragma unroll
    for (int mi = 0; mi < 4; mi++)
      af[mi] = *reinterpret_cast<const bf16x8*>(&As[buf][(mi * 16 + l15) * 32 + g * 8]);
#pragma unroll
    for (int ni = 0; ni < 2; ni++)
      bfr[ni] = *reinterpret_cast<const bf16x8*>(&Bs[buf][(w * 32 + ni * 16 + l15) * 32 + g * 8]);
#pragma unroll
    for (int mi = 0; mi < 4; mi++)
#pragma unroll
      for (int ni = 0; ni < 2; ni++)
        acc[mi][ni] = mfma16(af[mi], bfr[ni], acc[mi][ni]);
  }

  float bv[2];
#pragma unroll
  for (int ni = 0; ni < 2; ni++) bv[ni] = bias[n0 + w * 32 + ni * 16 + l15];

#pragma unroll
  for (int mi = 0; mi < 4; mi++)
#pragma unroll
    for (int ni = 0; ni < 2; ni++)
#pragma unroll
      for (int r = 0; r < 4; r++) {
        int gm = m0 + mi * 16 + g * 4 + r;
        int gn = n0 + w * 32 + ni * 16 + l15;
        out[(size_t)gm * N + gn] = acc[mi][ni][r] + bv[ni];
      }
}

// Flash attention, causal. Grid 1024 (all co-resident, 4 blocks/CU).
// bid -> (xcd, bh, tile) with per-CU balanced tiles {24+s, 23-s, 8+s, 7-s}.
// Double-buffered K/V LDS (32KB), stage-after-barrier. Swapped QK^T; P in regs.
// Chain-minimized softmax: per-lane l partial, trigger-only max (no per-iter shfl).
__global__ __launch_bounds__(256, 4) void attn_kernel(
    const u16* __restrict__ Q, const u16* __restrict__ Kt,
    const u16* __restrict__ Vt, u16* __restrict__ Y)
{
  __shared__ u16 smK[2][4096];  // [buf][64 keys][64 d]   (swizzled slots)
  __shared__ u16 smV[2][4096];  // [buf][64 d][64 keys]   (swizzled slots)
  const int tid = threadIdx.x;
  const int lane = tid & 63, w = tid >> 6;
  const int l15 = lane & 15, g = lane >> 4;
  const int bid = blockIdx.x;          // 0..1023
  const int q = bid >> 8;              // round 0..3 (same CU across rounds)
  const int rr = bid & 255;
  const int xcd = rr & 7;
  const int cu = (rr >> 3) & 31;       // CU slot within XCD
  const int bh = xcd * 4 + (cu & 3);   // 4 bh pinned per XCD
  const int s = cu >> 2;               // 0..7
  int tile;
  if (q == 0) tile = 24 + s;
  else if (q == 1) tile = 23 - s;
  else if (q == 2) tile = 8 + s;
  else tile = 7 - s;
  const int b = bh >> 4, h = bh & 15;
  const int xs = l15 & 7;  // read-side XOR

  const int nt = tile + 1;
  const int q0 = tile * 64 + w * 16;
  const int qg = q0 + l15;

  const size_t bhs = (size_t)bh;
  const u16* Qp = Q + bhs * SEQ * HD;
  const u16* Kp = Kt + bhs * SEQ * HD;
  const u16* Vp = Vt + bhs * HD * SEQ;  // [d][s]

  int srow[2], sslot[2];
#pragma unroll
  for (int it = 0; it < 2; it++) {
    int idx = it * 256 + tid;
    srow[it] = idx >> 3;
    sslot[it] = (idx & 7) ^ (srow[it] & 7);  // pre-swizzled global source slot
  }
  auto stage = [&](int buf, int kt) {
#pragma unroll
    for (int it = 0; it < 2; it++) {
      int idx = it * 256 + tid;
      gload16(Kp + (size_t)(kt + srow[it]) * HD + sslot[it] * 8, &smK[buf][idx * 8]);
      gload16(Vp + (size_t)srow[it] * SEQ + kt + sslot[it] * 8, &smV[buf][idx * 8]);
    }
  };

  const float QSC = 0.125f * 1.44269504088896f;  // 1/sqrt(64) * log2(e)
  const float NEG = -__builtin_inff();

  // Q fragments (B operand, sigma1)
  bf16x8 tq0 = *reinterpret_cast<const bf16x8*>(Qp + (size_t)qg * HD + g * 8);
  bf16x8 tq1 = *reinterpret_cast<const bf16x8*>(Qp + (size_t)qg * HD + 32 + g * 8);
  stage(0, 0);
  bf16x8 qf[2];
#pragma unroll
  for (int jj = 0; jj < 8; jj++) {
    qf[0][jj] = (__bf16)((float)tq0[jj] * QSC);
    qf[1][jj] = (__bf16)((float)tq1[jj] * QSC);
  }

  float m_run = NEG;
  float l_lane = 0.0f;   // per-lane partial; cross-lane reduced AFTER the loop
  f32x4 o[4] = {};       // O^T[d][q]: d = db*16 + g*4 + r, q = l15

  // one iteration body; MASKED resolves to a constant after inlining
  auto iter_body = [&](int t, bool MASKED) __attribute__((always_inline)) {
    const int kt = t * 64;
    const int buf = t & 1;
    __syncthreads();  // stage(t) landed (issued a full iteration ago); buf^1 readers done
    if (t + 1 < nt) stage(buf ^ 1, kt + 64);
    const u16* K_ = smK[buf];
    const u16* V_ = smV[buf];

    // ---- QK^T: S^T (log2 domain), key = kt + sub*16 + g*4 + r, q = l15
    f32x4 sa[4];
#pragma unroll
    for (int sub = 0; sub < 4; sub++) {
      int row = sub * 16 + l15;
      bf16x8 k0 = *reinterpret_cast<const bf16x8*>(&K_[row * 64 + ((0 + g) ^ xs) * 8]);
      bf16x8 k1 = *reinterpret_cast<const bf16x8*>(&K_[row * 64 + ((4 + g) ^ xs) * 8]);
      f32x4 a = {0.f, 0.f, 0.f, 0.f};
      a = mfma16(k0, qf[0], a);
      a = mfma16(k1, qf[1], a);
      sa[sub] = a;
    }

    float p[16];
    if (MASKED) {
#pragma unroll
      for (int sub = 0; sub < 4; sub++)
#pragma unroll
        for (int r = 0; r < 4; r++) {
          int key = kt + sub * 16 + g * 4 + r;
          p[sub * 4 + r] = (key <= qg) ? sa[sub][r] : NEG;
        }
    } else {
#pragma unroll
      for (int sub = 0; sub < 4; sub++)
#pragma unroll
        for (int r = 0; r < 4; r++) p[sub * 4 + r] = sa[sub][r];
    }

    // ---- per-LANE max tree (no cross-lane shfl in the common path)
    float a0 = fmaxf(fmaxf(p[0], p[1]), p[2]);
    float a1 = fmaxf(fmaxf(p[3], p[4]), p[5]);
    float a2 = fmaxf(fmaxf(p[6], p[7]), p[8]);
    float a3 = fmaxf(fmaxf(p[9], p[10]), p[11]);
    float a4 = fmaxf(fmaxf(p[12], p[13]), p[14]);
    float b0 = fmaxf(fmaxf(a0, a1), p[15]);
    float tloc = fmaxf(fmaxf(b0, a2), fmaxf(a3, a4));

    // trigger-only rescale: rare (first tile, then ~never for N(0,1) scores)
    if (__any(tloc > m_run + 11.0f)) {
      float tmax = tloc;
      tmax = fmaxf(tmax, __shfl_xor(tmax, 16));
      tmax = fmaxf(tmax, __shfl_xor(tmax, 32));
      float mnew = fmaxf(m_run, tmax);
      float fs = __builtin_amdgcn_exp2f(m_run - mnew);  // 0 when m_run=-inf
      l_lane *= fs;
#pragma unroll
      for (int db = 0; db < 4; db++) o[db] *= fs;
      m_run = mnew;
    }

    // ---- P = 2^(p - m_run); per-lane partial sum; pack via compiler cvt_pk
    float pe[16];
    float s4[4] = {0.f, 0.f, 0.f, 0.f};
#pragma unroll
    for (int i = 0; i < 16; i++) {
      pe[i] = __builtin_amdgcn_exp2f(p[i] - m_run);
      s4[i & 3] += pe[i];
    }

    // ---- O^T += V^T * P^T; sigma2(g,j) = (j>>2)*16 + g*4 + (j&3)
#pragma unroll
    for (int half = 0; half < 2; half++) {
      bf16x8 pb;
#pragma unroll
      for (int jj = 0; jj < 8; jj++) pb[jj] = (__bf16)pe[8 * half + jj];
      const int s0 = ((4 * half + (g >> 1)) ^ xs) * 8 + 4 * (g & 1);
      const int s1 = ((4 * half + 2 + (g >> 1)) ^ xs) * 8 + 4 * (g & 1);
#pragma unroll
      for (int db = 0; db < 4; db++) {
        int vbase = (db * 16 + l15) * 64;
        u16x4 v0 = *reinterpret_cast<const u16x4*>(&V_[vbase + s0]);
        u16x4 v1 = *reinterpret_cast<const u16x4*>(&V_[vbase + s1]);
        u16x8 vau;
#pragma unroll
        for (int jj = 0; jj < 4; jj++) { vau[jj] = v0[jj]; vau[jj + 4] = v1[jj]; }
        bf16x8 va = __builtin_bit_cast(bf16x8, vau);
        o[db] = mfma16(va, pb, o[db]);
      }
    }

    l_lane += (s4[0] + s4[1]) + (s4[2] + s4[3]);
  };

  for (int t = 0; t < nt - 1; t++) iter_body(t, false);
  iter_body(nt - 1, true);  // peeled: causal mask only here

  // ---- final cross-lane l reduce (once per tile, not per iteration)
  float l_tot = l_lane;
  l_tot += __shfl_xor(l_tot, 16);
  l_tot += __shfl_xor(l_tot, 32);
  float rl = 1.0f / l_tot;
#pragma unroll
  for (int db = 0; db < 4; db++) {
    u16x4 yo;
#pragma unroll
    for (int r = 0; r < 4; r++) yo[r] = f2bf(o[db][r] * rl);
    *reinterpret_cast<u16x4*>(
        Y + ((size_t)(b * SEQ) + qg) * HID + h * HD + db * 16 + g * 4) = yo;
  }
}

extern "C" void kernel_launch(void* const* d_in, const int* in_sizes, int n_in,
                              void* d_out, int out_size, void* d_ws, size_t ws_size,
                              hipStream_t stream) {
  const float* x  = (const float*)d_in[0];
  const float* Wq = (const float*)d_in[1];
  const float* bq = (const float*)d_in[2];
  const float* Wk = (const float*)d_in[3];
  const float* bk = (const float*)d_in[4];
  const float* Wv = (const float*)d_in[5];
  const float* bv = (const float*)d_in[6];
  const float* Wp = (const float*)d_in[7];
  const float* bp = (const float*)d_in[8];

  u16* ws = (u16*)d_ws;
  u16* xb  = ws; ws += NX;
  u16* wqb = ws; ws += NW;
  u16* wkb = ws; ws += NW;
  u16* wvb = ws; ws += NW;
  u16* wpb = ws; ws += NW;
  u16* Qb  = ws; ws += NX;
  u16* Kb  = ws; ws += NX;
  u16* Vtb = ws; ws += NX;
  u16* Yb  = ws; ws += NX;   // total ~48 MB of d_ws

  const unsigned cvtBlocks = (unsigned)((NX + 4 * NW) / 4 / 256);  // 8192
  cvt_all<<<cvtBlocks, 256, 0, stream>>>(x, Wq, Wk, Wv, Wp, xb, wqb, wkb, wvb, wpb);

  qkv_gemm<<<dim3(24, 32), 256, 0, stream>>>(xb, wqb, wkb, wvb, bq, bk, bv, Qb, Kb, Vtb);

  attn_kernel<<<dim3(1024), 256, 0, stream>>>(Qb, Kb, Vtb, Yb);

  gemm_out<<<dim3(8, 64), 256, 0, stream>>>(Yb, wpb, bp, (float*)d_out);
}

// Round 10
// 114.223 us; speedup vs baseline: 1.0016x; 1.0010x over previous
//
#include <hip/hip_runtime.h>

// CausalSelfAttention: B=2 S=2048 H=16 D=64 HID=1024, fp32 in/out, bf16 MFMA compute.
//
// R7 changes vs R6 (attn inner loop only — chain surgery):
//  - Deferred l-sum: per-lane partial l (rescale multiplies it; fs is q-uniform),
//    single cross-lane reduce AFTER the key loop. Removes 2 shfl/iter.
//  - Trigger-only max: per-lane max tree + __any(local > m+11) vcc check; full
//    cross-lane max only on the (rare) trigger. Removes 2 shfl/iter from the chain.
//  - Masked last iteration peeled out of the loop (no mask branch in main body).
//  Grid/balance/staging identical to R6 (1024 blocks, 4/CU, XCD-pinned, dbuf LDS).
//
// MFMA layout discipline: each MFMA's operand k-slot bijection is CHOSEN and used
// consistently for BOTH its A and B operands -> result invariant to the true HW
// bijection. QK uses sigma1(g,j)=g*8+j; PV uses sigma2(g,j)=(j>>2)*16+g*4+(j&3)
// (matches QK^T C/D register layout). C/D: col = lane&15, row = (lane>>4)*4 + reg.

typedef unsigned short u16;
typedef float f32x4 __attribute__((ext_vector_type(4)));
typedef __bf16 bf16x8 __attribute__((ext_vector_type(8)));
typedef unsigned short u16x4 __attribute__((ext_vector_type(4)));
typedef unsigned short u16x8 __attribute__((ext_vector_type(8)));

constexpr int Bn = 2, SEQ = 2048, NH = 16, HD = 64, HID = 1024;
constexpr size_t NX = (size_t)Bn * SEQ * HID;  // 4,194,304
constexpr size_t NW = (size_t)HID * HID;       // 1,048,576 = 1<<20

__device__ __forceinline__ u16 f2bf(float f) {
  unsigned u = __float_as_uint(f);
  u += 0x7fff + ((u >> 16) & 1);  // RNE
  return (u16)(u >> 16);
}

__device__ __forceinline__ f32x4 mfma16(bf16x8 a, bf16x8 b, f32x4 c) {
  return __builtin_amdgcn_mfma_f32_16x16x32_bf16(a, b, c, 0, 0, 0);
}

__device__ __forceinline__ void gload16(const u16* g, u16* l) {
  __builtin_amdgcn_global_load_lds(
      (const __attribute__((address_space(1))) unsigned int*)(const void*)g,
      (__attribute__((address_space(3))) unsigned int*)(void*)l, 16, 0, 0);
}

// One dispatch converting x, Wq, Wk, Wv, Wp to bf16.
__global__ void cvt_all(const float* __restrict__ x,
                        const float* __restrict__ Wq, const float* __restrict__ Wk,
                        const float* __restrict__ Wv, const float* __restrict__ Wp,
                        u16* __restrict__ xb, u16* __restrict__ wqb, u16* __restrict__ wkb,
                        u16* __restrict__ wvb, u16* __restrict__ wpb) {
  size_t i = ((size_t)blockIdx.x * blockDim.x + threadIdx.x) * 4;
  const float* s; u16* d; size_t off;
  if (i < NX) { s = x; d = xb; off = i; }
  else {
    size_t k = i - NX;
    int id = (int)(k >> 20);
    off = k & (NW - 1);
    s = (id == 0) ? Wq : (id == 1) ? Wk : (id == 2) ? Wv : Wp;
    d = (id == 0) ? wqb : (id == 1) ? wkb : (id == 2) ? wvb : wpb;
  }
  float4 v = *reinterpret_cast<const float4*>(s + off);
  u16x4 o = {f2bf(v.x), f2bf(v.y), f2bf(v.z), f2bf(v.w)};
  *reinterpret_cast<u16x4*>(d + off) = o;
}

// Fused QKV projection: grid (24 n-panels, 32 m-tiles); x-fastest dispatch ->
// weight panel x pinned to XCD x&7 (3 panels/XCD L2-resident).
// Q,K -> [b,h,s,d]; V -> [b,h,d,s] via LDS transpose epilogue.
__global__ __launch_bounds__(256) void qkv_gemm(
    const u16* __restrict__ A,
    const u16* __restrict__ W0, const u16* __restrict__ W1, const u16* __restrict__ W2,
    const float* __restrict__ b0, const float* __restrict__ b1, const float* __restrict__ b2,
    u16* __restrict__ out0, u16* __restrict__ out1, u16* __restrict__ out2)
{
  constexpr int K = HID;
  __shared__ u16 smem[16384];  // As[2]=smem[0..8191], Bs[2]=smem[8192..16383]; epilogue reuse 32KB
  const int tid = threadIdx.x;
  const int lane = tid & 63, w = tid >> 6;
  const int wr = w >> 1, wc = w & 1;
  const int l15 = lane & 15, g = lane >> 4;
  const int m0 = blockIdx.y * 128;
  const int n0g = blockIdx.x * 128;
  const int id = n0g >> 10;
  const int n0 = n0g & (HID - 1);
  const u16* Bm = (id == 0) ? W0 : (id == 1) ? W1 : W2;
  const float* bias = (id == 0) ? b0 : (id == 1) ? b1 : b2;

  auto stage = [&](int buf, int kt) {
#pragma unroll
    for (int i = 0; i < 2; i++) {
      int chunk = tid + 256 * i;
      int r = chunk >> 2, c = (chunk & 3) << 3;
      gload16(&A[(size_t)(m0 + r) * K + kt + c], &smem[buf * 4096 + chunk * 8]);
      gload16(&Bm[(size_t)(n0 + r) * K + kt + c], &smem[8192 + buf * 4096 + chunk * 8]);
    }
  };

  f32x4 acc[4][4] = {};
  stage(0, 0);

  for (int ki = 0; ki < 32; ki++) {
    const int buf = ki & 1;
    __syncthreads();  // vmcnt(0): stage(ki) landed (issued a full compute phase ago)
    if (ki + 1 < 32) stage(buf ^ 1, (ki + 1) * 32);
    const u16* As = &smem[buf * 4096];
    const u16* Bs = &smem[8192 + buf * 4096];
    bf16x8 af[4], bfr[4];
#pragma unroll
    for (int mi = 0; mi < 4; mi++)
      af[mi] = *reinterpret_cast<const bf16x8*>(&As[(wr * 64 + mi * 16 + l15) * 32 + g * 8]);
#pragma unroll
    for (int ni = 0; ni < 4; ni++)
      bfr[ni] = *reinterpret_cast<const bf16x8*>(&Bs[(wc * 64 + ni * 16 + l15) * 32 + g * 8]);
#pragma unroll
    for (int mi = 0; mi < 4; mi++)
#pragma unroll
      for (int ni = 0; ni < 4; ni++)
        acc[mi][ni] = mfma16(af[mi], bfr[ni], acc[mi][ni]);
  }

  float bv[4];
#pragma unroll
  for (int ni = 0; ni < 4; ni++) bv[ni] = bias[n0 + wc * 64 + ni * 16 + l15];

  if (id == 2) {
    // V^T: transpose 128(sq) x 128(d) tile through swizzled LDS, store along s.
    __syncthreads();  // K-loop LDS reads done everywhere; reuse smem
#pragma unroll
    for (int mi = 0; mi < 4; mi++)
#pragma unroll
      for (int ni = 0; ni < 4; ni++) {
        u16x4 pk;
#pragma unroll
        for (int r = 0; r < 4; r++) pk[r] = f2bf(acc[mi][ni][r] + bv[ni]);
        int d_loc = wc * 64 + ni * 16 + l15;
        int sq_base = wr * 64 + mi * 16 + g * 4;
        *reinterpret_cast<u16x4*>(
            &smem[d_loc * 128 + (sq_base ^ ((d_loc & 7) << 4))]) = pk;
      }
    __syncthreads();
    const int bb = m0 >> 11;
    const int sq0 = m0 & (SEQ - 1);
#pragma unroll
    for (int i = 0; i < 8; i++) {
      int chunk = tid + 256 * i;           // 0..2047
      int d_loc = chunk >> 4;              // 0..127
      int sqc = (chunk & 15) << 3;         // 0..120, step 8
      u16x8 val = *reinterpret_cast<const u16x8*>(
          &smem[d_loc * 128 + (sqc ^ ((d_loc & 7) << 4))]);
      int gn = n0 + d_loc;
      int hh = gn >> 6, dd = gn & 63;
      *reinterpret_cast<u16x8*>(
          &out2[((size_t)(bb * NH + hh) * HD + dd) * SEQ + sq0 + sqc]) = val;
    }
  } else {
    u16* out = (id == 0) ? out0 : out1;
#pragma unroll
    for (int mi = 0; mi < 4; mi++)
#pragma unroll
      for (int ni = 0; ni < 4; ni++)
#pragma unroll
        for (int r = 0; r < 4; r++) {
          int gm = m0 + wr * 64 + mi * 16 + g * 4 + r;
          int gn = n0 + wc * 64 + ni * 16 + l15;
          int bb = gm >> 11, sq = gm & (SEQ - 1);
          int hh = gn >> 6, d = gn & 63;
          out[((size_t)(bb * NH + hh) * SEQ + sq) * HD + d] = f2bf(acc[mi][ni][r] + bv[ni]);
        }
  }
}

// Output projection: out = Y @ Wp^T + bp, fp32. 64(M)x128(N) tiles, grid (8, 64):
// weight panel x pinned to XCD x (exactly one 256KB panel per XCD).
__global__ __launch_bounds__(256) void gemm_out(
    const u16* __restrict__ A, const u16* __restrict__ Bm,
    const float* __restrict__ bias, float* __restrict__ out)
{
  constexpr int K = HID, N = HID;
  __shared__ u16 As[2][64 * 32];
  __shared__ u16 Bs[2][128 * 32];
  const int tid = threadIdx.x;
  const int lane = tid & 63, w = tid >> 6;
  const int l15 = lane & 15, g = lane >> 4;
  const int m0 = blockIdx.y * 64, n0 = blockIdx.x * 128;

  auto stage = [&](int buf, int kt) {
    {
      int r = tid >> 2, c = (tid & 3) << 3;
      gload16(&A[(size_t)(m0 + r) * K + kt + c], &As[buf][tid * 8]);
    }
#pragma unroll
    for (int i = 0; i < 2; i++) {
      int chunk = tid + 256 * i;
      int r = chunk >> 2, c = (chunk & 3) << 3;
      gload16(&Bm[(size_t)(n0 + r) * K + kt + c], &Bs[buf][chunk * 8]);
    }
  };

  f32x4 acc[4][2] = {};
  stage(0, 0);

  for (int ki = 0; ki < 32; ki++) {
    const int buf = ki & 1;
    __syncthreads();
    if (ki + 1 < 32) stage(buf ^ 1, (ki + 1) * 32);
    bf16x8 af[4], bfr[2];
#pragma unroll
    for (int mi = 0; mi < 4; mi++)
      af[mi] = *reinterpret_cast<const bf16x8*>(&As[buf][(mi * 16 + l15) * 32 + g * 8]);
#pragma unroll
    for (int ni = 0; ni < 2; ni++)
      bfr[ni] = *reinterpret_cast<const bf16x8*>(&Bs[buf][(w * 32 + ni * 16 + l15) * 32 + g * 8]);
#pragma unroll
    for (int mi = 0; mi < 4; mi++)
#pragma unroll
      for (int ni = 0; ni < 2; ni++)
        acc[mi][ni] = mfma16(af[mi], bfr[ni], acc[mi][ni]);
  }

  float bv[2];
#pragma unroll
  for (int ni = 0; ni < 2; ni++) bv[ni] = bias[n0 + w * 32 + ni * 16 + l15];

#pragma unroll
  for (int mi = 0; mi < 4; mi++)
#pragma unroll
    for (int ni = 0; ni < 2; ni++)
#pragma unroll
      for (int r = 0; r < 4; r++) {
        int gm = m0 + mi * 16 + g * 4 + r;
        int gn = n0 + w * 32 + ni * 16 + l15;
        out[(size_t)gm * N + gn] = acc[mi][ni][r] + bv[ni];
      }
}

// Flash attention, causal. Grid 1024 (all co-resident, 4 blocks/CU).
// bid -> (xcd, bh, tile) with per-CU balanced tiles {24+s, 23-s, 8+s, 7-s}.
// Double-buffered K/V LDS (32KB), stage-after-barrier. Swapped QK^T; P in regs.
// Chain-minimized softmax: per-lane l partial, trigger-only max (no per-iter shfl).
__global__ __launch_bounds__(256, 4) void attn_kernel(
    const u16* __restrict__ Q, const u16* __restrict__ Kt,
    const u16* __restrict__ Vt, u16* __restrict__ Y)
{
  __shared__ u16 smK[2][4096];  // [buf][64 keys][64 d]   (swizzled slots)
  __shared__ u16 smV[2][4096];  // [buf][64 d][64 keys]   (swizzled slots)
  const int tid = threadIdx.x;
  const int lane = tid & 63, w = tid >> 6;
  const int l15 = lane & 15, g = lane >> 4;
  const int bid = blockIdx.x;          // 0..1023
  const int q = bid >> 8;              // round 0..3 (same CU across rounds)
  const int rr = bid & 255;
  const int xcd = rr & 7;
  const int cu = (rr >> 3) & 31;       // CU slot within XCD
  const int bh = xcd * 4 + (cu & 3);   // 4 bh pinned per XCD
  const int s = cu >> 2;               // 0..7
  int tile;
  if (q == 0) tile = 24 + s;
  else if (q == 1) tile = 23 - s;
  else if (q == 2) tile = 8 + s;
  else tile = 7 - s;
  const int b = bh >> 4, h = bh & 15;
  const int xs = l15 & 7;  // read-side XOR

  const int nt = tile + 1;
  const int q0 = tile * 64 + w * 16;
  const int qg = q0 + l15;

  const size_t bhs = (size_t)bh;
  const u16* Qp = Q + bhs * SEQ * HD;
  const u16* Kp = Kt + bhs * SEQ * HD;
  const u16* Vp = Vt + bhs * HD * SEQ;  // [d][s]

  int srow[2], sslot[2];
#pragma unroll
  for (int it = 0; it < 2; it++) {
    int idx = it * 256 + tid;
    srow[it] = idx >> 3;
    sslot[it] = (idx & 7) ^ (srow[it] & 7);  // pre-swizzled global source slot
  }
  auto stage = [&](int buf, int kt) {
#pragma unroll
    for (int it = 0; it < 2; it++) {
      int idx = it * 256 + tid;
      gload16(Kp + (size_t)(kt + srow[it]) * HD + sslot[it] * 8, &smK[buf][idx * 8]);
      gload16(Vp + (size_t)srow[it] * SEQ + kt + sslot[it] * 8, &smV[buf][idx * 8]);
    }
  };

  const float QSC = 0.125f * 1.44269504088896f;  // 1/sqrt(64) * log2(e)
  const float NEG = -__builtin_inff();

  // Q fragments (B operand, sigma1)
  bf16x8 tq0 = *reinterpret_cast<const bf16x8*>(Qp + (size_t)qg * HD + g * 8);
  bf16x8 tq1 = *reinterpret_cast<const bf16x8*>(Qp + (size_t)qg * HD + 32 + g * 8);
  stage(0, 0);
  bf16x8 qf[2];
#pragma unroll
  for (int jj = 0; jj < 8; jj++) {
    qf[0][jj] = (__bf16)((float)tq0[jj] * QSC);
    qf[1][jj] = (__bf16)((float)tq1[jj] * QSC);
  }

  float m_run = NEG;
  float l_lane = 0.0f;   // per-lane partial; cross-lane reduced AFTER the loop
  f32x4 o[4] = {};       // O^T[d][q]: d = db*16 + g*4 + r, q = l15

  // one iteration body; MASKED resolves to a constant after inlining
  auto iter_body = [&](int t, bool MASKED) __attribute__((always_inline)) {
    const int kt = t * 64;
    const int buf = t & 1;
    __syncthreads();  // stage(t) landed (issued a full iteration ago); buf^1 readers done
    if (t + 1 < nt) stage(buf ^ 1, kt + 64);
    const u16* K_ = smK[buf];
    const u16* V_ = smV[buf];

    // ---- QK^T: S^T (log2 domain), key = kt + sub*16 + g*4 + r, q = l15
    f32x4 sa[4];
#pragma unroll
    for (int sub = 0; sub < 4; sub++) {
      int row = sub * 16 + l15;
      bf16x8 k0 = *reinterpret_cast<const bf16x8*>(&K_[row * 64 + ((0 + g) ^ xs) * 8]);
      bf16x8 k1 = *reinterpret_cast<const bf16x8*>(&K_[row * 64 + ((4 + g) ^ xs) * 8]);
      f32x4 a = {0.f, 0.f, 0.f, 0.f};
      a = mfma16(k0, qf[0], a);
      a = mfma16(k1, qf[1], a);
      sa[sub] = a;
    }

    float p[16];
    if (MASKED) {
#pragma unroll
      for (int sub = 0; sub < 4; sub++)
#pragma unroll
        for (int r = 0; r < 4; r++) {
          int key = kt + sub * 16 + g * 4 + r;
          p[sub * 4 + r] = (key <= qg) ? sa[sub][r] : NEG;
        }
    } else {
#pragma unroll
      for (int sub = 0; sub < 4; sub++)
#pragma unroll
        for (int r = 0; r < 4; r++) p[sub * 4 + r] = sa[sub][r];
    }

    // ---- per-LANE max tree (no cross-lane shfl in the common path)
    float a0 = fmaxf(fmaxf(p[0], p[1]), p[2]);
    float a1 = fmaxf(fmaxf(p[3], p[4]), p[5]);
    float a2 = fmaxf(fmaxf(p[6], p[7]), p[8]);
    float a3 = fmaxf(fmaxf(p[9], p[10]), p[11]);
    float a4 = fmaxf(fmaxf(p[12], p[13]), p[14]);
    float b0 = fmaxf(fmaxf(a0, a1), p[15]);
    float tloc = fmaxf(fmaxf(b0, a2), fmaxf(a3, a4));

    // trigger-only rescale: rare (first tile, then ~never for N(0,1) scores)
    if (__any(tloc > m_run + 11.0f)) {
      float tmax = tloc;
      tmax = fmaxf(tmax, __shfl_xor(tmax, 16));
      tmax = fmaxf(tmax, __shfl_xor(tmax, 32));
      float mnew = fmaxf(m_run, tmax);
      float fs = __builtin_amdgcn_exp2f(m_run - mnew);  // 0 when m_run=-inf
      l_lane *= fs;
#pragma unroll
      for (int db = 0; db < 4; db++) o[db] *= fs;
      m_run = mnew;
    }

    // ---- P = 2^(p - m_run); per-lane partial sum; pack via compiler cvt_pk
    float pe[16];
    float s4[4] = {0.f, 0.f, 0.f, 0.f};
#pragma unroll
    for (int i = 0; i < 16; i++) {
      pe[i] = __builtin_amdgcn_exp2f(p[i] - m_run);
      s4[i & 3] += pe[i];
    }

    // ---- O^T += V^T * P^T; sigma2(g,j) = (j>>2)*16 + g*4 + (j&3)
#pragma unroll
    for (int half = 0; half < 2; half++) {
      bf16x8 pb;
#pragma unroll
      for (int jj = 0; jj < 8; jj++) pb[jj] = (__bf16)pe[8 * half + jj];
      const int s0 = ((4 * half + (g >> 1)) ^ xs) * 8 + 4 * (g & 1);
      const int s1 = ((4 * half + 2 + (g >> 1)) ^ xs) * 8 + 4 * (g & 1);
#pragma unroll
      for (int db = 0; db < 4; db++) {
        int vbase = (db * 16 + l15) * 64;
        u16x4 v0 = *reinterpret_cast<const u16x4*>(&V_[vbase + s0]);
        u16x4 v1 = *reinterpret_cast<const u16x4*>(&V_[vbase + s1]);
        u16x8 vau;
#pragma unroll
        for (int jj = 0; jj < 4; jj++) { vau[jj] = v0[jj]; vau[jj + 4] = v1[jj]; }
        bf16x8 va = __builtin_bit_cast(bf16x8, vau);
        o[db] = mfma16(va, pb, o[db]);
      }
    }

    l_lane += (s4[0] + s4[1]) + (s4[2] + s4[3]);
  };

  for (int t = 0; t < nt - 1; t++) iter_body(t, false);
  iter_body(nt - 1, true);  // peeled: causal mask only here

  // ---- final cross-lane l reduce (once per tile, not per iteration)
  float l_tot = l_lane;
  l_tot += __shfl_xor(l_tot, 16);
  l_tot += __shfl_xor(l_tot, 32);
  float rl = 1.0f / l_tot;
#pragma unroll
  for (int db = 0; db < 4; db++) {
    u16x4 yo;
#pragma unroll
    for (int r = 0; r < 4; r++) yo[r] = f2bf(o[db][r] * rl);
    *reinterpret_cast<u16x4*>(
        Y + ((size_t)(b * SEQ) + qg) * HID + h * HD + db * 16 + g * 4) = yo;
  }
}

extern "C" void kernel_launch(void* const* d_in, const int* in_sizes, int n_in,
                              void* d_out, int out_size, void* d_ws, size_t ws_size,
                              hipStream_t stream) {
  const float* x  = (const float*)d_in[0];
  const float* Wq = (const float*)d_in[1];
  const float* bq = (const float*)d_in[2];
  const float* Wk = (const float*)d_in[3];
  const float* bk = (const float*)d_in[4];
  const float* Wv = (const float*)d_in[5];
  const float* bv = (const float*)d_in[6];
  const float* Wp = (const float*)d_in[7];
  const float* bp = (const float*)d_in[8];

  u16* ws = (u16*)d_ws;
  u16* xb  = ws; ws += NX;
  u16* wqb = ws; ws += NW;
  u16* wkb = ws; ws += NW;
  u16* wvb = ws; ws += NW;
  u16* wpb = ws; ws += NW;
  u16* Qb  = ws; ws += NX;
  u16* Kb  = ws; ws += NX;
  u16* Vtb = ws; ws += NX;
  u16* Yb  = ws; ws += NX;   // total ~48 MB of d_ws

  const unsigned cvtBlocks = (unsigned)((NX + 4 * NW) / 4 / 256);  // 8192
  cvt_all<<<cvtBlocks, 256, 0, stream>>>(x, Wq, Wk, Wv, Wp, xb, wqb, wkb, wvb, wpb);

  qkv_gemm<<<dim3(24, 32), 256, 0, stream>>>(xb, wqb, wkb, wvb, bq, bk, bv, Qb, Kb, Vtb);

  attn_kernel<<<dim3(1024), 256, 0, stream>>>(Qb, Kb, Vtb, Yb);

  gemm_out<<<dim3(8, 64), 256, 0, stream>>>(Yb, wpb, bp, (float*)d_out);
}

// Round 11
// 112.112 us; speedup vs baseline: 1.0204x; 1.0188x over previous
//
#include <hip/hip_runtime.h>

// CausalSelfAttention: B=2 S=2048 H=16 D=64 HID=1024, fp32 in/out, bf16 MFMA compute.
//
// R8 changes vs R7 (attn makespan):
//  - Split-K: tiles with >16 iters split into A/B key-range halves (max piece = 16
//    iters). 48 pieces/bh x 32 bh = 1536 blocks, static LPT (longest-first) piece
//    table, XCD-pinned, 5 blocks/CU resident. Breaks the 51%/32-iter makespan floor.
//  - Split halves store unnormalized partial O (bf16) + per-q (m,l) in the dead
//    xb/wqb workspace regions; attn_combine (512 blocks) merges and writes Y.
//  Inner loop / staging / softmax identical to R7.
//
// MFMA layout discipline: each MFMA's operand k-slot bijection is CHOSEN and used
// consistently for BOTH its A and B operands -> result invariant to the true HW
// bijection. QK uses sigma1(g,j)=g*8+j; PV uses sigma2(g,j)=(j>>2)*16+g*4+(j&3)
// (matches QK^T C/D register layout). C/D: col = lane&15, row = (lane>>4)*4 + reg.

typedef unsigned short u16;
typedef float f32x4 __attribute__((ext_vector_type(4)));
typedef __bf16 bf16x8 __attribute__((ext_vector_type(8)));
typedef unsigned short u16x4 __attribute__((ext_vector_type(4)));
typedef unsigned short u16x8 __attribute__((ext_vector_type(8)));

constexpr int Bn = 2, SEQ = 2048, NH = 16, HD = 64, HID = 1024;
constexpr size_t NX = (size_t)Bn * SEQ * HID;  // 4,194,304
constexpr size_t NW = (size_t)HID * HID;       // 1,048,576 = 1<<20

// Piece table: 48 pieces per bh, sorted by length desc (LPT dispatch order).
// part: 0 = full tile, 1 = A half (never masked), 2 = B half (masked last iter).
__device__ __constant__ unsigned char PT_TILE[48] = {
  31,31,30,15, 30,29,29,28,14, 28,27,27,26,13, 26,25,25,24,12,
  24,23,23,22,11, 22,21,21,20,10, 20,19,19,18,9, 18,17,17,16,8,
  16,7, 6,5,4,3,2,1,0};
__device__ __constant__ unsigned char PT_PART[48] = {
  1,2,1,0, 2,1,2,1,0, 2,1,2,1,0, 2,1,2,1,0,
  2,1,2,1,0, 2,1,2,1,0, 2,1,2,1,0, 2,1,2,1,0,
  2,0, 0,0,0,0,0,0,0};
__device__ __constant__ unsigned char PT_START[48] = {
  0,16,0,0, 16,0,15,0,0, 15,0,14,0,0, 14,0,13,0,0,
  13,0,12,0,0, 12,0,11,0,0, 11,0,10,0,0, 10,0,9,0,0,
  9,0, 0,0,0,0,0,0,0};
__device__ __constant__ unsigned char PT_NIT[48] = {
  16,16,16,16, 15,15,15,15,15, 14,14,14,14,14, 13,13,13,13,13,
  12,12,12,12,12, 11,11,11,11,11, 10,10,10,10,10, 9,9,9,9,9,
  8,8, 7,6,5,4,3,2,1};

__device__ __forceinline__ u16 f2bf(float f) {
  unsigned u = __float_as_uint(f);
  u += 0x7fff + ((u >> 16) & 1);  // RNE
  return (u16)(u >> 16);
}

__device__ __forceinline__ float bf2f(u16 u) {
  return __uint_as_float(((unsigned)u) << 16);
}

__device__ __forceinline__ f32x4 mfma16(bf16x8 a, bf16x8 b, f32x4 c) {
  return __builtin_amdgcn_mfma_f32_16x16x32_bf16(a, b, c, 0, 0, 0);
}

__device__ __forceinline__ void gload16(const u16* g, u16* l) {
  __builtin_amdgcn_global_load_lds(
      (const __attribute__((address_space(1))) unsigned int*)(const void*)g,
      (__attribute__((address_space(3))) unsigned int*)(void*)l, 16, 0, 0);
}

// One dispatch converting x, Wq, Wk, Wv, Wp to bf16.
__global__ void cvt_all(const float* __restrict__ x,
                        const float* __restrict__ Wq, const float* __restrict__ Wk,
                        const float* __restrict__ Wv, const float* __restrict__ Wp,
                        u16* __restrict__ xb, u16* __restrict__ wqb, u16* __restrict__ wkb,
                        u16* __restrict__ wvb, u16* __restrict__ wpb) {
  size_t i = ((size_t)blockIdx.x * blockDim.x + threadIdx.x) * 4;
  const float* s; u16* d; size_t off;
  if (i < NX) { s = x; d = xb; off = i; }
  else {
    size_t k = i - NX;
    int id = (int)(k >> 20);
    off = k & (NW - 1);
    s = (id == 0) ? Wq : (id == 1) ? Wk : (id == 2) ? Wv : Wp;
    d = (id == 0) ? wqb : (id == 1) ? wkb : (id == 2) ? wvb : wpb;
  }
  float4 v = *reinterpret_cast<const float4*>(s + off);
  u16x4 o = {f2bf(v.x), f2bf(v.y), f2bf(v.z), f2bf(v.w)};
  *reinterpret_cast<u16x4*>(d + off) = o;
}

// Fused QKV projection: grid (24 n-panels, 32 m-tiles); x-fastest dispatch ->
// weight panel x pinned to XCD x&7 (3 panels/XCD L2-resident).
// Q,K -> [b,h,s,d]; V -> [b,h,d,s] via LDS transpose epilogue.
__global__ __launch_bounds__(256) void qkv_gemm(
    const u16* __restrict__ A,
    const u16* __restrict__ W0, const u16* __restrict__ W1, const u16* __restrict__ W2,
    const float* __restrict__ b0, const float* __restrict__ b1, const float* __restrict__ b2,
    u16* __restrict__ out0, u16* __restrict__ out1, u16* __restrict__ out2)
{
  constexpr int K = HID;
  __shared__ u16 smem[16384];  // As[2]=smem[0..8191], Bs[2]=smem[8192..16383]; epilogue reuse 32KB
  const int tid = threadIdx.x;
  const int lane = tid & 63, w = tid >> 6;
  const int wr = w >> 1, wc = w & 1;
  const int l15 = lane & 15, g = lane >> 4;
  const int m0 = blockIdx.y * 128;
  const int n0g = blockIdx.x * 128;
  const int id = n0g >> 10;
  const int n0 = n0g & (HID - 1);
  const u16* Bm = (id == 0) ? W0 : (id == 1) ? W1 : W2;
  const float* bias = (id == 0) ? b0 : (id == 1) ? b1 : b2;

  auto stage = [&](int buf, int kt) {
#pragma unroll
    for (int i = 0; i < 2; i++) {
      int chunk = tid + 256 * i;
      int r = chunk >> 2, c = (chunk & 3) << 3;
      gload16(&A[(size_t)(m0 + r) * K + kt + c], &smem[buf * 4096 + chunk * 8]);
      gload16(&Bm[(size_t)(n0 + r) * K + kt + c], &smem[8192 + buf * 4096 + chunk * 8]);
    }
  };

  f32x4 acc[4][4] = {};
  stage(0, 0);

  for (int ki = 0; ki < 32; ki++) {
    const int buf = ki & 1;
    __syncthreads();  // vmcnt(0): stage(ki) landed (issued a full compute phase ago)
    if (ki + 1 < 32) stage(buf ^ 1, (ki + 1) * 32);
    const u16* As = &smem[buf * 4096];
    const u16* Bs = &smem[8192 + buf * 4096];
    bf16x8 af[4], bfr[4];
#pragma unroll
    for (int mi = 0; mi < 4; mi++)
      af[mi] = *reinterpret_cast<const bf16x8*>(&As[(wr * 64 + mi * 16 + l15) * 32 + g * 8]);
#pragma unroll
    for (int ni = 0; ni < 4; ni++)
      bfr[ni] = *reinterpret_cast<const bf16x8*>(&Bs[(wc * 64 + ni * 16 + l15) * 32 + g * 8]);
#pragma unroll
    for (int mi = 0; mi < 4; mi++)
#pragma unroll
      for (int ni = 0; ni < 4; ni++)
        acc[mi][ni] = mfma16(af[mi], bfr[ni], acc[mi][ni]);
  }

  float bv[4];
#pragma unroll
  for (int ni = 0; ni < 4; ni++) bv[ni] = bias[n0 + wc * 64 + ni * 16 + l15];

  if (id == 2) {
    // V^T: transpose 128(sq) x 128(d) tile through swizzled LDS, store along s.
    __syncthreads();  // K-loop LDS reads done everywhere; reuse smem
#pragma unroll
    for (int mi = 0; mi < 4; mi++)
#pragma unroll
      for (int ni = 0; ni < 4; ni++) {
        u16x4 pk;
#pragma unroll
        for (int r = 0; r < 4; r++) pk[r] = f2bf(acc[mi][ni][r] + bv[ni]);
        int d_loc = wc * 64 + ni * 16 + l15;
        int sq_base = wr * 64 + mi * 16 + g * 4;
        *reinterpret_cast<u16x4*>(
            &smem[d_loc * 128 + (sq_base ^ ((d_loc & 7) << 4))]) = pk;
      }
    __syncthreads();
    const int bb = m0 >> 11;
    const int sq0 = m0 & (SEQ - 1);
#pragma unroll
    for (int i = 0; i < 8; i++) {
      int chunk = tid + 256 * i;           // 0..2047
      int d_loc = chunk >> 4;              // 0..127
      int sqc = (chunk & 15) << 3;         // 0..120, step 8
      u16x8 val = *reinterpret_cast<const u16x8*>(
          &smem[d_loc * 128 + (sqc ^ ((d_loc & 7) << 4))]);
      int gn = n0 + d_loc;
      int hh = gn >> 6, dd = gn & 63;
      *reinterpret_cast<u16x8*>(
          &out2[((size_t)(bb * NH + hh) * HD + dd) * SEQ + sq0 + sqc]) = val;
    }
  } else {
    u16* out = (id == 0) ? out0 : out1;
#pragma unroll
    for (int mi = 0; mi < 4; mi++)
#pragma unroll
      for (int ni = 0; ni < 4; ni++)
#pragma unroll
        for (int r = 0; r < 4; r++) {
          int gm = m0 + wr * 64 + mi * 16 + g * 4 + r;
          int gn = n0 + wc * 64 + ni * 16 + l15;
          int bb = gm >> 11, sq = gm & (SEQ - 1);
          int hh = gn >> 6, d = gn & 63;
          out[((size_t)(bb * NH + hh) * SEQ + sq) * HD + d] = f2bf(acc[mi][ni][r] + bv[ni]);
        }
  }
}

// Output projection: out = Y @ Wp^T + bp, fp32. 64(M)x128(N) tiles, grid (8, 64):
// weight panel x pinned to XCD x (exactly one 256KB panel per XCD).
__global__ __launch_bounds__(256) void gemm_out(
    const u16* __restrict__ A, const u16* __restrict__ Bm,
    const float* __restrict__ bias, float* __restrict__ out)
{
  constexpr int K = HID, N = HID;
  __shared__ u16 As[2][64 * 32];
  __shared__ u16 Bs[2][128 * 32];
  const int tid = threadIdx.x;
  const int lane = tid & 63, w = tid >> 6;
  const int l15 = lane & 15, g = lane >> 4;
  const int m0 = blockIdx.y * 64, n0 = blockIdx.x * 128;

  auto stage = [&](int buf, int kt) {
    {
      int r = tid >> 2, c = (tid & 3) << 3;
      gload16(&A[(size_t)(m0 + r) * K + kt + c], &As[buf][tid * 8]);
    }
#pragma unroll
    for (int i = 0; i < 2; i++) {
      int chunk = tid + 256 * i;
      int r = chunk >> 2, c = (chunk & 3) << 3;
      gload16(&Bm[(size_t)(n0 + r) * K + kt + c], &Bs[buf][chunk * 8]);
    }
  };

  f32x4 acc[4][2] = {};
  stage(0, 0);

  for (int ki = 0; ki < 32; ki++) {
    const int buf = ki & 1;
    __syncthreads();
    if (ki + 1 < 32) stage(buf ^ 1, (ki + 1) * 32);
    bf16x8 af[4], bfr[2];
#pragma unroll
    for (int mi = 0; mi < 4; mi++)
      af[mi] = *reinterpret_cast<const bf16x8*>(&As[buf][(mi * 16 + l15) * 32 + g * 8]);
#pragma unroll
    for (int ni = 0; ni < 2; ni++)
      bfr[ni] = *reinterpret_cast<const bf16x8*>(&Bs[buf][(w * 32 + ni * 16 + l15) * 32 + g * 8]);
#pragma unroll
    for (int mi = 0; mi < 4; mi++)
#pragma unroll
      for (int ni = 0; ni < 2; ni++)
        acc[mi][ni] = mfma16(af[mi], bfr[ni], acc[mi][ni]);
  }

  float bv[2];
#pragma unroll
  for (int ni = 0; ni < 2; ni++) bv[ni] = bias[n0 + w * 32 + ni * 16 + l15];

#pragma unroll
  for (int mi = 0; mi < 4; mi++)
#pragma unroll
    for (int ni = 0; ni < 2; ni++)
#pragma unroll
      for (int r = 0; r < 4; r++) {
        int gm = m0 + mi * 16 + g * 4 + r;
        int gn = n0 + w * 32 + ni * 16 + l15;
        out[(size_t)gm * N + gn] = acc[mi][ni][r] + bv[ni];
      }
}

// Flash attention, causal, split-K. Grid 1536: bid -> (xcd, bh, piece) with the
// LPT piece table. Full pieces write Y; A/B halves write partial O(bf16)+ml(f32).
// Double-buffered K/V LDS (32KB), stage-after-barrier. Swapped QK^T; P in regs.
__global__ __launch_bounds__(256, 4) void attn_kernel(
    const u16* __restrict__ Q, const u16* __restrict__ Kt,
    const u16* __restrict__ Vt, u16* __restrict__ Y,
    u16* __restrict__ OP, float2* __restrict__ MLP)
{
  __shared__ u16 smK[2][4096];  // [buf][64 keys][64 d]   (swizzled slots)
  __shared__ u16 smV[2][4096];  // [buf][64 d][64 keys]   (swizzled slots)
  const int tid = threadIdx.x;
  const int lane = tid & 63, w = tid >> 6;
  const int l15 = lane & 15, g = lane >> 4;
  const int bid = blockIdx.x;          // 0..1535
  const int xcd = bid & 7;
  const int r_ = bid >> 3;             // 0..191
  const int bh = xcd * 4 + (r_ & 3);   // 4 bh pinned per XCD
  const int piece = r_ >> 2;           // 0..47, LPT order
  const int tile = PT_TILE[piece];
  const int part = PT_PART[piece];
  const int it0 = PT_START[piece];
  const int nit = PT_NIT[piece];
  const int b = bh >> 4, h = bh & 15;
  const int xs = l15 & 7;  // read-side XOR

  const int q0 = tile * 64 + w * 16;
  const int qg = q0 + l15;

  const size_t bhs = (size_t)bh;
  const u16* Qp = Q + bhs * SEQ * HD;
  const u16* Kp = Kt + bhs * SEQ * HD;
  const u16* Vp = Vt + bhs * HD * SEQ;  // [d][s]

  int srow[2], sslot[2];
#pragma unroll
  for (int it = 0; it < 2; it++) {
    int idx = it * 256 + tid;
    srow[it] = idx >> 3;
    sslot[it] = (idx & 7) ^ (srow[it] & 7);  // pre-swizzled global source slot
  }
  auto stage = [&](int buf, int kt) {
#pragma unroll
    for (int it = 0; it < 2; it++) {
      int idx = it * 256 + tid;
      gload16(Kp + (size_t)(kt + srow[it]) * HD + sslot[it] * 8, &smK[buf][idx * 8]);
      gload16(Vp + (size_t)srow[it] * SEQ + kt + sslot[it] * 8, &smV[buf][idx * 8]);
    }
  };

  const float QSC = 0.125f * 1.44269504088896f;  // 1/sqrt(64) * log2(e)
  const float NEG = -__builtin_inff();

  // Q fragments (B operand, sigma1)
  bf16x8 tq0 = *reinterpret_cast<const bf16x8*>(Qp + (size_t)qg * HD + g * 8);
  bf16x8 tq1 = *reinterpret_cast<const bf16x8*>(Qp + (size_t)qg * HD + 32 + g * 8);
  stage(0, it0 * 64);
  bf16x8 qf[2];
#pragma unroll
  for (int jj = 0; jj < 8; jj++) {
    qf[0][jj] = (__bf16)((float)tq0[jj] * QSC);
    qf[1][jj] = (__bf16)((float)tq1[jj] * QSC);
  }

  float m_run = NEG;
  float l_lane = 0.0f;   // per-lane partial; cross-lane reduced AFTER the loop
  f32x4 o[4] = {};       // O^T[d][q]: d = db*16 + g*4 + r, q = l15

  // one iteration body; MASKED resolves to a constant after inlining
  auto iter_body = [&](int i, bool MASKED) __attribute__((always_inline)) {
    const int kt = (it0 + i) * 64;
    const int buf = i & 1;
    __syncthreads();  // stage(i) landed (issued a full iteration ago); buf^1 readers done
    if (i + 1 < nit) stage(buf ^ 1, kt + 64);
    const u16* K_ = smK[buf];
    const u16* V_ = smV[buf];

    // ---- QK^T: S^T (log2 domain), key = kt + sub*16 + g*4 + r, q = l15
    f32x4 sa[4];
#pragma unroll
    for (int sub = 0; sub < 4; sub++) {
      int row = sub * 16 + l15;
      bf16x8 k0 = *reinterpret_cast<const bf16x8*>(&K_[row * 64 + ((0 + g) ^ xs) * 8]);
      bf16x8 k1 = *reinterpret_cast<const bf16x8*>(&K_[row * 64 + ((4 + g) ^ xs) * 8]);
      f32x4 a = {0.f, 0.f, 0.f, 0.f};
      a = mfma16(k0, qf[0], a);
      a = mfma16(k1, qf[1], a);
      sa[sub] = a;
    }

    float p[16];
    if (MASKED) {
#pragma unroll
      for (int sub = 0; sub < 4; sub++)
#pragma unroll
        for (int r = 0; r < 4; r++) {
          int key = kt + sub * 16 + g * 4 + r;
          p[sub * 4 + r] = (key <= qg) ? sa[sub][r] : NEG;
        }
    } else {
#pragma unroll
      for (int sub = 0; sub < 4; sub++)
#pragma unroll
        for (int r = 0; r < 4; r++) p[sub * 4 + r] = sa[sub][r];
    }

    // ---- per-LANE max tree (no cross-lane shfl in the common path)
    float a0 = fmaxf(fmaxf(p[0], p[1]), p[2]);
    float a1 = fmaxf(fmaxf(p[3], p[4]), p[5]);
    float a2 = fmaxf(fmaxf(p[6], p[7]), p[8]);
    float a3 = fmaxf(fmaxf(p[9], p[10]), p[11]);
    float a4 = fmaxf(fmaxf(p[12], p[13]), p[14]);
    float b0 = fmaxf(fmaxf(a0, a1), p[15]);
    float tloc = fmaxf(fmaxf(b0, a2), fmaxf(a3, a4));

    // trigger-only rescale: rare (first tile, then ~never for N(0,1) scores)
    if (__any(tloc > m_run + 11.0f)) {
      float tmax = tloc;
      tmax = fmaxf(tmax, __shfl_xor(tmax, 16));
      tmax = fmaxf(tmax, __shfl_xor(tmax, 32));
      float mnew = fmaxf(m_run, tmax);
      float fs = __builtin_amdgcn_exp2f(m_run - mnew);  // 0 when m_run=-inf
      l_lane *= fs;
#pragma unroll
      for (int db = 0; db < 4; db++) o[db] *= fs;
      m_run = mnew;
    }

    // ---- P = 2^(p - m_run); per-lane partial sum; pack via compiler cvt_pk
    float pe[16];
    float s4[4] = {0.f, 0.f, 0.f, 0.f};
#pragma unroll
    for (int i2 = 0; i2 < 16; i2++) {
      pe[i2] = __builtin_amdgcn_exp2f(p[i2] - m_run);
      s4[i2 & 3] += pe[i2];
    }

    // ---- O^T += V^T * P^T; sigma2(g,j) = (j>>2)*16 + g*4 + (j&3)
#pragma unroll
    for (int half = 0; half < 2; half++) {
      bf16x8 pb;
#pragma unroll
      for (int jj = 0; jj < 8; jj++) pb[jj] = (__bf16)pe[8 * half + jj];
      const int s0 = ((4 * half + (g >> 1)) ^ xs) * 8 + 4 * (g & 1);
      const int s1 = ((4 * half + 2 + (g >> 1)) ^ xs) * 8 + 4 * (g & 1);
#pragma unroll
      for (int db = 0; db < 4; db++) {
        int vbase = (db * 16 + l15) * 64;
        u16x4 v0 = *reinterpret_cast<const u16x4*>(&V_[vbase + s0]);
        u16x4 v1 = *reinterpret_cast<const u16x4*>(&V_[vbase + s1]);
        u16x8 vau;
#pragma unroll
        for (int jj = 0; jj < 4; jj++) { vau[jj] = v0[jj]; vau[jj + 4] = v1[jj]; }
        bf16x8 va = __builtin_bit_cast(bf16x8, vau);
        o[db] = mfma16(va, pb, o[db]);
      }
    }

    l_lane += (s4[0] + s4[1]) + (s4[2] + s4[3]);
  };

  if (part == 1) {
    // A half: no iteration is ever masked (keys < 1024 <= tile*64)
    for (int i = 0; i < nit; i++) iter_body(i, false);
  } else {
    for (int i = 0; i < nit - 1; i++) iter_body(i, false);
    iter_body(nit - 1, true);  // peeled: causal mask only here
  }

  // ---- final cross-lane l reduce (once per piece)
  float l_tot = l_lane;
  l_tot += __shfl_xor(l_tot, 16);
  l_tot += __shfl_xor(l_tot, 32);

  if (part == 0) {
    float rl = 1.0f / l_tot;
#pragma unroll
    for (int db = 0; db < 4; db++) {
      u16x4 yo;
#pragma unroll
      for (int r = 0; r < 4; r++) yo[r] = f2bf(o[db][r] * rl);
      *reinterpret_cast<u16x4*>(
          Y + ((size_t)(b * SEQ) + qg) * HID + h * HD + db * 16 + g * 4) = yo;
    }
  } else {
    // partial store: O (bf16, unnormalized) at [slot][q][d]; ml (m_run, l_tot)
    const int slot = (bh * 16 + (tile - 16)) * 2 + (part - 1);
    u16* op = OP + (size_t)slot * 4096 + (w * 16 + l15) * 64;
#pragma unroll
    for (int db = 0; db < 4; db++) {
      u16x4 po;
#pragma unroll
      for (int r = 0; r < 4; r++) po[r] = f2bf(o[db][r]);
      *reinterpret_cast<u16x4*>(op + db * 16 + g * 4) = po;
    }
    if (g == 0) {
      float2 ml; ml.x = m_run; ml.y = l_tot;
      MLP[slot * 64 + w * 16 + l15] = ml;
    }
  }
}

// Combine split halves: Y = (OA*2^(mA-m) + OB*2^(mB-m)) / (lA*2^(mA-m) + lB*2^(mB-m)).
// Grid 512 (xcd-pinned same as attn). Thread t: q = t>>2, d-chunk = (t&3)*16.
__global__ __launch_bounds__(256) void attn_combine(
    const u16* __restrict__ OP, const float2* __restrict__ MLP, u16* __restrict__ Y)
{
  const int bid = blockIdx.x;          // 0..511
  const int xcd = bid & 7;
  const int r_ = bid >> 3;             // 0..63
  const int bh = xcd * 4 + (r_ & 3);
  const int t16 = r_ >> 2;             // 0..15
  const int tile = 16 + t16;
  const int b = bh >> 4, h = bh & 15;
  const int slotA = (bh * 16 + t16) * 2, slotB = slotA + 1;

  const int t = threadIdx.x;
  const int q = t >> 2, dc = (t & 3) << 4;

  float2 mlA = MLP[slotA * 64 + q];
  float2 mlB = MLP[slotB * 64 + q];
  float m = fmaxf(mlA.x, mlB.x);
  float wA = __builtin_amdgcn_exp2f(mlA.x - m);
  float wB = __builtin_amdgcn_exp2f(mlB.x - m);
  float rl = 1.0f / (mlA.y * wA + mlB.y * wB);

  const u16* pa = OP + (size_t)slotA * 4096 + q * 64 + dc;
  const u16* pb = OP + (size_t)slotB * 4096 + q * 64 + dc;
  u16x8 a0 = *reinterpret_cast<const u16x8*>(pa);
  u16x8 a1 = *reinterpret_cast<const u16x8*>(pa + 8);
  u16x8 b0 = *reinterpret_cast<const u16x8*>(pb);
  u16x8 b1 = *reinterpret_cast<const u16x8*>(pb + 8);
  u16x8 y0, y1;
#pragma unroll
  for (int j = 0; j < 8; j++) {
    y0[j] = f2bf((bf2f(a0[j]) * wA + bf2f(b0[j]) * wB) * rl);
    y1[j] = f2bf((bf2f(a1[j]) * wA + bf2f(b1[j]) * wB) * rl);
  }
  u16* yp = Y + ((size_t)(b * SEQ) + tile * 64 + q) * HID + h * HD + dc;
  *reinterpret_cast<u16x8*>(yp) = y0;
  *reinterpret_cast<u16x8*>(yp + 8) = y1;
}

extern "C" void kernel_launch(void* const* d_in, const int* in_sizes, int n_in,
                              void* d_out, int out_size, void* d_ws, size_t ws_size,
                              hipStream_t stream) {
  const float* x  = (const float*)d_in[0];
  const float* Wq = (const float*)d_in[1];
  const float* bq = (const float*)d_in[2];
  const float* Wk = (const float*)d_in[3];
  const float* bk = (const float*)d_in[4];
  const float* Wv = (const float*)d_in[5];
  const float* bv = (const float*)d_in[6];
  const float* Wp = (const float*)d_in[7];
  const float* bp = (const float*)d_in[8];

  u16* ws = (u16*)d_ws;
  u16* xb  = ws; ws += NX;
  u16* wqb = ws; ws += NW;
  u16* wkb = ws; ws += NW;
  u16* wvb = ws; ws += NW;
  u16* wpb = ws; ws += NW;
  u16* Qb  = ws; ws += NX;
  u16* Kb  = ws; ws += NX;
  u16* Vtb = ws; ws += NX;
  u16* Yb  = ws; ws += NX;   // total ~48 MB of d_ws

  // after qkv_gemm, xb (8MB) and wqb (2MB) are dead -> reuse for split-K partials
  u16*    OP  = xb;             // 1024 slots x 4096 bf16 = 8 MiB (exact fit)
  float2* MLP = (float2*)wqb;   // 1024 slots x 64 float2 = 512 KiB

  const unsigned cvtBlocks = (unsigned)((NX + 4 * NW) / 4 / 256);  // 8192
  cvt_all<<<cvtBlocks, 256, 0, stream>>>(x, Wq, Wk, Wv, Wp, xb, wqb, wkb, wvb, wpb);

  qkv_gemm<<<dim3(24, 32), 256, 0, stream>>>(xb, wqb, wkb, wvb, bq, bk, bv, Qb, Kb, Vtb);

  attn_kernel<<<dim3(1536), 256, 0, stream>>>(Qb, Kb, Vtb, Yb, OP, MLP);

  attn_combine<<<dim3(512), 256, 0, stream>>>(OP, MLP, Yb);

  gemm_out<<<dim3(8, 64), 256, 0, stream>>>(Yb, wpb, bp, (float*)d_out);
}